// Round 1
// baseline (781.907 us; speedup 1.0000x reference)
//
#include <hip/hip_runtime.h>

#define F_IN 256
#define HC   128   // HEADS * C_OUT
#define NEG  0.2f
#define MNODES 16  // nodes per block in projection

// ---------------- projection: xsrc = x@Wsrc, xdst = x@Wdst ----------------
// 256 threads: t<128 -> Wsrc col t ; t>=128 -> Wdst col t-128. 16 nodes/block.
// x addresses are block-uniform -> scalar loads; W reads coalesced (L2-resident).
__global__ void k_proj(const float* __restrict__ x, const float* __restrict__ Ws,
                       const float* __restrict__ Wd, float* __restrict__ xsrc,
                       float* __restrict__ xdst, int N) {
    const int col  = threadIdx.x & 127;
    const int half = threadIdx.x >> 7;
    const float* __restrict__ W = half ? Wd : Ws;
    float* __restrict__ o = half ? xdst : xsrc;
    const int n0 = blockIdx.x * MNODES;
    if (n0 >= N) return;

    float acc[MNODES];
#pragma unroll
    for (int n = 0; n < MNODES; ++n) acc[n] = 0.f;

    if (n0 + MNODES <= N) {
        const float* __restrict__ xp = x + (size_t)n0 * F_IN;
#pragma unroll 4
        for (int k = 0; k < F_IN; ++k) {
            float w = W[k * HC + col];
#pragma unroll
            for (int n = 0; n < MNODES; ++n) acc[n] += xp[n * F_IN + k] * w;
        }
#pragma unroll
        for (int n = 0; n < MNODES; ++n)
            o[(size_t)(n0 + n) * HC + col] = acc[n];
    } else {
        for (int n = 0; n < MNODES; ++n) {
            int node = n0 + n;
            if (node >= N) break;
            float a = 0.f;
            const float* __restrict__ xp = x + (size_t)node * F_IN;
            for (int k = 0; k < F_IN; ++k) a += xp[k] * W[k * HC + col];
            o[(size_t)node * HC + col] = a;
        }
    }
}

// ---------------- CSR build ----------------
__global__ void k_hist(const int* __restrict__ dst, int E, int* __restrict__ counts) {
    int i = blockIdx.x * blockDim.x + threadIdx.x;
    int stride = gridDim.x * blockDim.x;
    for (; i < E; i += stride) atomicAdd(&counts[dst[i]], 1);
}

// per-block inclusive scan of counts -> offsets[i+1] (local), block totals -> bsums
__global__ void k_scan1(const int* __restrict__ counts, int N,
                        int* __restrict__ offsets, int* __restrict__ bsums) {
    __shared__ int s[256];
    int t = threadIdx.x;
    int i = blockIdx.x * 256 + t;
    int v = (i < N) ? counts[i] : 0;
    s[t] = v;
    __syncthreads();
#pragma unroll
    for (int d = 1; d < 256; d <<= 1) {
        int add = (t >= d) ? s[t - d] : 0;
        __syncthreads();
        s[t] += add;
        __syncthreads();
    }
    if (i < N) offsets[i + 1] = s[t];
    if (t == 255) bsums[blockIdx.x] = s[255];
}

// single-block exclusive scan of block sums (NB <= 1024)
__global__ void k_scan2(const int* __restrict__ bsums, int NB, int* __restrict__ boffs) {
    __shared__ int s[1024];
    int t = threadIdx.x;
    int v = (t < NB) ? bsums[t] : 0;
    s[t] = v;
    __syncthreads();
#pragma unroll
    for (int d = 1; d < 1024; d <<= 1) {
        int add = (t >= d) ? s[t - d] : 0;
        __syncthreads();
        s[t] += add;
        __syncthreads();
    }
    boffs[t] = s[t] - v;  // exclusive
}

// finalize offsets (add block offsets), init cursor = exclusive offset
__global__ void k_fill(const int* __restrict__ counts, int N, int* __restrict__ offsets,
                       const int* __restrict__ boffs, int* __restrict__ cursor) {
    int i = blockIdx.x * blockDim.x + threadIdx.x;
    if (i == 0) offsets[0] = 0;
    if (i < N) {
        int incl = offsets[i + 1] + boffs[i >> 8];
        offsets[i + 1] = incl;
        cursor[i] = incl - counts[i];
    }
}

__global__ void k_scatter(const int* __restrict__ src, const int* __restrict__ dst, int E,
                          int* __restrict__ cursor, int* __restrict__ csr) {
    int i = blockIdx.x * blockDim.x + threadIdx.x;
    int stride = gridDim.x * blockDim.x;
    for (; i < E; i += stride) {
        int d = dst[i];
        int pos = atomicAdd(&cursor[d], 1);
        csr[pos] = src[i];
    }
}

// ---------------- per-node online-softmax aggregation ----------------
// one wave (64 lanes) per destination node; lane = channel c; 2 heads in 2 regs.
__global__ void k_agg(const float* __restrict__ xsrc, const float* __restrict__ xdst,
                      const int* __restrict__ csr, const int* __restrict__ offsets,
                      const float* __restrict__ att, const float* __restrict__ bias,
                      float* __restrict__ out, int N) {
    int wid  = threadIdx.x >> 6;
    int lane = threadIdx.x & 63;
    int node = blockIdx.x * (blockDim.x >> 6) + wid;
    if (node >= N) return;

    int beg = offsets[node];
    int end = offsets[node + 1];

    float xd0 = xdst[(size_t)node * HC + lane];
    float xd1 = xdst[(size_t)node * HC + 64 + lane];
    float a0  = att[lane];
    float a1  = att[64 + lane];

    float m0 = -__builtin_inff(), m1 = -__builtin_inff();
    float l0 = 0.f, l1 = 0.f, o0 = 0.f, o1 = 0.f;

    for (int e = beg; e < end; ++e) {
        int j = csr[e];
        float xj0 = xsrc[(size_t)j * HC + lane];
        float xj1 = xsrc[(size_t)j * HC + 64 + lane];
        float e0 = xj0 + xd0; e0 = (e0 > 0.f) ? e0 : NEG * e0;
        float e1 = xj1 + xd1; e1 = (e1 > 0.f) ? e1 : NEG * e1;
        float p0 = e0 * a0;
        float p1 = e1 * a1;
#pragma unroll
        for (int s = 1; s < 64; s <<= 1) {
            p0 += __shfl_xor(p0, s, 64);
            p1 += __shfl_xor(p1, s, 64);
        }
        // online softmax update, head 0
        float mn0 = fmaxf(m0, p0);
        float w0  = __expf(p0 - mn0);
        float sc0 = __expf(m0 - mn0);   // exp(-inf)=0 on first edge
        l0 = l0 * sc0 + w0;
        o0 = o0 * sc0 + w0 * xj0;
        m0 = mn0;
        // head 1
        float mn1 = fmaxf(m1, p1);
        float w1  = __expf(p1 - mn1);
        float sc1 = __expf(m1 - mn1);
        l1 = l1 * sc1 + w1;
        o1 = o1 * sc1 + w1 * xj1;
        m1 = mn1;
    }

    out[(size_t)node * HC + lane]      = o0 / (l0 + 1e-16f) + bias[lane];
    out[(size_t)node * HC + 64 + lane] = o1 / (l1 + 1e-16f) + bias[64 + lane];
}

extern "C" void kernel_launch(void* const* d_in, const int* in_sizes, int n_in,
                              void* d_out, int out_size, void* d_ws, size_t ws_size,
                              hipStream_t stream) {
    const float* x    = (const float*)d_in[0];
    const int*   ei   = (const int*)d_in[1];
    const float* Ws   = (const float*)d_in[2];
    const float* Wd   = (const float*)d_in[3];
    const float* att  = (const float*)d_in[4];
    const float* bias = (const float*)d_in[5];
    float* out = (float*)d_out;

    const int N = in_sizes[0] / F_IN;
    const int E = in_sizes[1] / 2;
    const int* src = ei;
    const int* dst = ei + E;

    char* ws = (char*)d_ws;
    size_t off = 0;
    auto alloc = [&](size_t bytes) -> char* {
        off = (off + 255) & ~(size_t)255;
        char* p = ws + off;
        off += bytes;
        return p;
    };
    float* xsrc    = (float*)alloc((size_t)N * HC * sizeof(float));  // 51.2 MB
    float* xdst    = (float*)alloc((size_t)N * HC * sizeof(float));  // 51.2 MB
    int*   counts  = (int*)alloc((size_t)N * sizeof(int));
    int*   offsets = (int*)alloc(((size_t)N + 1) * sizeof(int));
    int*   cursor  = (int*)alloc((size_t)N * sizeof(int));
    int*   bsums   = (int*)alloc(1024 * sizeof(int));
    int*   boffs   = (int*)alloc(1024 * sizeof(int));
    int*   csr     = (int*)alloc((size_t)E * sizeof(int));

    hipMemsetAsync(counts, 0, (size_t)N * sizeof(int), stream);

    k_proj<<<(N + MNODES - 1) / MNODES, 256, 0, stream>>>(x, Ws, Wd, xsrc, xdst, N);
    k_hist<<<2048, 256, 0, stream>>>(dst, E, counts);
    int NB = (N + 255) / 256;
    k_scan1<<<NB, 256, 0, stream>>>(counts, N, offsets, bsums);
    k_scan2<<<1, 1024, 0, stream>>>(bsums, NB, boffs);
    k_fill<<<(N + 255) / 256, 256, 0, stream>>>(counts, N, offsets, boffs, cursor);
    k_scatter<<<2048, 256, 0, stream>>>(src, dst, E, cursor, csr);
    k_agg<<<(N + 3) / 4, 256, 0, stream>>>(xsrc, xdst, csr, offsets, att, bias, out, N);
}

// Round 2
// 471.875 us; speedup vs baseline: 1.6570x; 1.6570x over previous
//
#include <hip/hip_runtime.h>

#define F_IN 256
#define HC   128   // HEADS * C_OUT
#define NEG  0.2f

typedef __attribute__((ext_vector_type(8))) short bf16x8;
typedef __attribute__((ext_vector_type(4))) float f32x4;

// round-to-nearest-even fp32 -> bf16 (as ushort)
__device__ __forceinline__ unsigned short f2b(float f) {
    unsigned int u = __float_as_uint(f);
    return (unsigned short)((u + 0x7FFFu + ((u >> 16) & 1u)) >> 16);
}

// ---------------- pack W = [Ws | Wd] (256x256) into B-fragment order ----------------
// PB[((nt*8 + t)*64 + lane)*8 + j] = bf16( B[k = 32t + (lane>>4)*8 + j][n = nt*16 + (lane&15)] )
__global__ void k_pack(const float* __restrict__ Ws, const float* __restrict__ Wd,
                       unsigned short* __restrict__ PB) {
    int tid = blockIdx.x * 256 + threadIdx.x;   // 8192 threads
    int nt  = tid >> 9;        // 0..15
    int rem = tid & 511;
    int t   = rem >> 6;        // 0..7
    int l   = rem & 63;
    int n     = nt * 16 + (l & 15);
    int kbase = 32 * t + (l >> 4) * 8;
    union { bf16x8 v; unsigned short u[8]; } o;
#pragma unroll
    for (int j = 0; j < 8; ++j) {
        int k = kbase + j;
        float w = (n < HC) ? Ws[k * HC + n] : Wd[k * HC + (n - HC)];
        o.u[j] = f2b(w);
    }
    *(bf16x8*)(PB + (size_t)tid * 8) = o.v;
}

// ---------------- MFMA projection: [xsrc | xdst] = x @ [Ws | Wd] ----------------
// Block = 4 waves = 64 rows x 256 cols. Wave w: cols [64w, 64w+64), 4 M-tiles x 4 N-tiles.
__global__ __launch_bounds__(256) void k_gemm(const float* __restrict__ x,
                                              const unsigned short* __restrict__ PB,
                                              float* __restrict__ xsrc,
                                              float* __restrict__ xdst, int N) {
    const int wave = threadIdx.x >> 6;
    const int lane = threadIdx.x & 63;
    const int m = lane & 15;
    const int q = lane >> 4;
    const long row0 = (long)blockIdx.x * 64;

    f32x4 acc[4][4];   // [mt][g]
#pragma unroll
    for (int a = 0; a < 4; ++a)
#pragma unroll
        for (int b = 0; b < 4; ++b) acc[a][b] = (f32x4){0.f, 0.f, 0.f, 0.f};

#pragma unroll
    for (int t = 0; t < 8; ++t) {
        const int k0 = t * 32 + q * 8;
        bf16x8 af[4];
#pragma unroll
        for (int mt = 0; mt < 4; ++mt) {
            long r = row0 + mt * 16 + m;
            if (r >= N) r = N - 1;                    // clamp (stores are guarded)
            const float* p = x + r * F_IN + k0;       // 32B-aligned
            float4 a0 = *(const float4*)p;
            float4 a1 = *(const float4*)(p + 4);
            union { bf16x8 v; unsigned short u[8]; } c;
            c.u[0] = f2b(a0.x); c.u[1] = f2b(a0.y); c.u[2] = f2b(a0.z); c.u[3] = f2b(a0.w);
            c.u[4] = f2b(a1.x); c.u[5] = f2b(a1.y); c.u[6] = f2b(a1.z); c.u[7] = f2b(a1.w);
            af[mt] = c.v;
        }
#pragma unroll
        for (int g = 0; g < 4; ++g) {
            const int nt = wave * 4 + g;
            bf16x8 bf = *(const bf16x8*)(PB + ((size_t)(nt * 8 + t) * 64 + lane) * 8);
#pragma unroll
            for (int mt = 0; mt < 4; ++mt)
                acc[mt][g] = __builtin_amdgcn_mfma_f32_16x16x32_bf16(af[mt], bf, acc[mt][g], 0, 0, 0);
        }
    }

    // D layout: col = lane&15 (within N-tile), row = q*4 + r (within M-tile)
#pragma unroll
    for (int mt = 0; mt < 4; ++mt) {
#pragma unroll
        for (int g = 0; g < 4; ++g) {
            const int nt = wave * 4 + g;
            const int n  = nt * 16 + m;
            float* o = (n < HC) ? xsrc : xdst;
            const int nn = (n < HC) ? n : n - HC;
#pragma unroll
            for (int r = 0; r < 4; ++r) {
                long row = row0 + mt * 16 + q * 4 + r;
                if (row < N) o[row * HC + nn] = acc[mt][g][r];
            }
        }
    }
}

// ---------------- CSR build ----------------
__global__ void k_hist(const int* __restrict__ dst, int E, int* __restrict__ counts) {
    int i = blockIdx.x * blockDim.x + threadIdx.x;
    int stride = gridDim.x * blockDim.x;
    for (; i < E; i += stride) atomicAdd(&counts[dst[i]], 1);
}

__global__ void k_scan1(const int* __restrict__ counts, int N,
                        int* __restrict__ offsets, int* __restrict__ bsums) {
    __shared__ int s[256];
    int t = threadIdx.x;
    int i = blockIdx.x * 256 + t;
    int v = (i < N) ? counts[i] : 0;
    s[t] = v;
    __syncthreads();
#pragma unroll
    for (int d = 1; d < 256; d <<= 1) {
        int add = (t >= d) ? s[t - d] : 0;
        __syncthreads();
        s[t] += add;
        __syncthreads();
    }
    if (i < N) offsets[i + 1] = s[t];
    if (t == 255) bsums[blockIdx.x] = s[255];
}

__global__ void k_scan2(const int* __restrict__ bsums, int NB, int* __restrict__ boffs) {
    __shared__ int s[1024];
    int t = threadIdx.x;
    int v = (t < NB) ? bsums[t] : 0;
    s[t] = v;
    __syncthreads();
#pragma unroll
    for (int d = 1; d < 1024; d <<= 1) {
        int add = (t >= d) ? s[t - d] : 0;
        __syncthreads();
        s[t] += add;
        __syncthreads();
    }
    boffs[t] = s[t] - v;  // exclusive
}

__global__ void k_fill(const int* __restrict__ counts, int N, int* __restrict__ offsets,
                       const int* __restrict__ boffs, int* __restrict__ cursor) {
    int i = blockIdx.x * blockDim.x + threadIdx.x;
    if (i == 0) offsets[0] = 0;
    if (i < N) {
        int incl = offsets[i + 1] + boffs[i >> 8];
        offsets[i + 1] = incl;
        cursor[i] = incl - counts[i];
    }
}

__global__ void k_scatter(const int* __restrict__ src, const int* __restrict__ dst, int E,
                          int* __restrict__ cursor, int* __restrict__ csr) {
    int i = blockIdx.x * blockDim.x + threadIdx.x;
    int stride = gridDim.x * blockDim.x;
    for (; i < E; i += stride) {
        int d = dst[i];
        int pos = atomicAdd(&cursor[d], 1);
        csr[pos] = src[i];
    }
}

// ---------------- per-node online-softmax aggregation ----------------
// one wave per destination node; lane = channel; 2 heads in 2 regs.
// Software-pipelined: next edge's gather issued before current edge's shuffle chain.
__global__ void k_agg(const float* __restrict__ xsrc, const float* __restrict__ xdst,
                      const int* __restrict__ csr, const int* __restrict__ offsets,
                      const float* __restrict__ att, const float* __restrict__ bias,
                      float* __restrict__ out, int N) {
    int wid  = threadIdx.x >> 6;
    int lane = threadIdx.x & 63;
    int node = blockIdx.x * (blockDim.x >> 6) + wid;
    if (node >= N) return;

    int beg = offsets[node];
    int end = offsets[node + 1];

    float xd0 = xdst[(size_t)node * HC + lane];
    float xd1 = xdst[(size_t)node * HC + 64 + lane];
    float a0  = att[lane];
    float a1  = att[64 + lane];

    float m0 = -__builtin_inff(), m1 = -__builtin_inff();
    float l0 = 0.f, l1 = 0.f, o0 = 0.f, o1 = 0.f;

    if (beg < end) {
        int j = csr[beg];
        float xj0 = xsrc[(size_t)j * HC + lane];
        float xj1 = xsrc[(size_t)j * HC + 64 + lane];
        for (int e = beg; e < end; ++e) {
            float cx0 = xj0, cx1 = xj1;
            if (e + 1 < end) {                    // prefetch next edge
                int jn = csr[e + 1];
                xj0 = xsrc[(size_t)jn * HC + lane];
                xj1 = xsrc[(size_t)jn * HC + 64 + lane];
            }
            float e0 = cx0 + xd0; e0 = (e0 > 0.f) ? e0 : NEG * e0;
            float e1 = cx1 + xd1; e1 = (e1 > 0.f) ? e1 : NEG * e1;
            float p0 = e0 * a0;
            float p1 = e1 * a1;
#pragma unroll
            for (int s = 1; s < 64; s <<= 1) {
                p0 += __shfl_xor(p0, s, 64);
                p1 += __shfl_xor(p1, s, 64);
            }
            float mn0 = fmaxf(m0, p0);
            float w0  = __expf(p0 - mn0);
            float sc0 = __expf(m0 - mn0);   // exp(-inf)=0 on first edge
            l0 = l0 * sc0 + w0;
            o0 = o0 * sc0 + w0 * cx0;
            m0 = mn0;
            float mn1 = fmaxf(m1, p1);
            float w1  = __expf(p1 - mn1);
            float sc1 = __expf(m1 - mn1);
            l1 = l1 * sc1 + w1;
            o1 = o1 * sc1 + w1 * cx1;
            m1 = mn1;
        }
    }

    out[(size_t)node * HC + lane]      = o0 / (l0 + 1e-16f) + bias[lane];
    out[(size_t)node * HC + 64 + lane] = o1 / (l1 + 1e-16f) + bias[64 + lane];
}

extern "C" void kernel_launch(void* const* d_in, const int* in_sizes, int n_in,
                              void* d_out, int out_size, void* d_ws, size_t ws_size,
                              hipStream_t stream) {
    const float* x    = (const float*)d_in[0];
    const int*   ei   = (const int*)d_in[1];
    const float* Ws   = (const float*)d_in[2];
    const float* Wd   = (const float*)d_in[3];
    const float* att  = (const float*)d_in[4];
    const float* bias = (const float*)d_in[5];
    float* out = (float*)d_out;

    const int N = in_sizes[0] / F_IN;
    const int E = in_sizes[1] / 2;
    const int* src = ei;
    const int* dst = ei + E;

    char* ws = (char*)d_ws;
    size_t off = 0;
    auto alloc = [&](size_t bytes) -> char* {
        off = (off + 255) & ~(size_t)255;
        char* p = ws + off;
        off += bytes;
        return p;
    };
    float* xsrc    = (float*)alloc((size_t)N * HC * sizeof(float));  // 51.2 MB
    float* xdst    = (float*)alloc((size_t)N * HC * sizeof(float));  // 51.2 MB
    unsigned short* PB = (unsigned short*)alloc(256 * 256 * sizeof(unsigned short)); // 128 KB
    int*   counts  = (int*)alloc((size_t)N * sizeof(int));
    int*   offsets = (int*)alloc(((size_t)N + 1) * sizeof(int));
    int*   cursor  = (int*)alloc((size_t)N * sizeof(int));
    int*   bsums   = (int*)alloc(1024 * sizeof(int));
    int*   boffs   = (int*)alloc(1024 * sizeof(int));
    int*   csr     = (int*)alloc((size_t)E * sizeof(int));

    hipMemsetAsync(counts, 0, (size_t)N * sizeof(int), stream);

    k_pack<<<32, 256, 0, stream>>>(Ws, Wd, PB);
    k_gemm<<<(N + 63) / 64, 256, 0, stream>>>(x, PB, xsrc, xdst, N);
    k_hist<<<2048, 256, 0, stream>>>(dst, E, counts);
    int NB = (N + 255) / 256;
    k_scan1<<<NB, 256, 0, stream>>>(counts, N, offsets, bsums);
    k_scan2<<<1, 1024, 0, stream>>>(bsums, NB, boffs);
    k_fill<<<(N + 255) / 256, 256, 0, stream>>>(counts, N, offsets, boffs, cursor);
    k_scatter<<<2048, 256, 0, stream>>>(src, dst, E, cursor, csr);
    k_agg<<<(N + 3) / 4, 256, 0, stream>>>(xsrc, xdst, csr, offsets, att, bias, out, N);
}